// Round 1
// baseline (347.473 us; speedup 1.0000x reference)
//
#include <hip/hip_runtime.h>

#define NB 32768
#define HPITCH 132   // LDS row pitch for 128-wide activations (+4 pad, 16B aligned)

// ---------- fast math helpers (v_exp_f32 / v_rcp_f32, ~1ulp: fine vs 2% threshold) ----------
__device__ __forceinline__ float rcp_f(float x){ return __builtin_amdgcn_rcpf(x); }
__device__ __forceinline__ float exp2_f(float x){ return __builtin_amdgcn_exp2f(x); }
__device__ __forceinline__ float tanh_f(float x){
  float e = exp2_f(x * 2.8853900817779268f);     // e^(2x)
  return (e - 1.0f) * rcp_f(e + 1.0f);
}
__device__ __forceinline__ float sigmoid_f(float x){
  return rcp_f(1.0f + exp2_f(-1.4426950408889634f * x));
}

// ---------- generic layer: C(64 x 128) = act(A(64 x K) @ W(K x 128) + b) ----------
// thread (tr,tc): rows 4tr..4tr+3, cols 8tc..8tc+7. A from LDS (pitch HPITCH) or global (pitch 256).
template<int K, int APITCH, bool DOTANH>
__device__ __forceinline__ void layerN128(const float* __restrict__ Asrc,
    const float* __restrict__ W, const float* __restrict__ bias,
    float* __restrict__ Odst, int tr, int tc)
{
  float acc[4][8];
#pragma unroll
  for (int r=0;r<4;++r)
#pragma unroll
    for (int c=0;c<8;++c) acc[r][c]=0.0f;

  const float* arow0 = Asrc + (4*tr+0)*APITCH;
  const float* arow1 = Asrc + (4*tr+1)*APITCH;
  const float* arow2 = Asrc + (4*tr+2)*APITCH;
  const float* arow3 = Asrc + (4*tr+3)*APITCH;
  const float* wp = W + 8*tc;

#pragma unroll 2
  for (int k=0;k<K;k+=4){
    float4 av[4];
    av[0] = *(const float4*)(arow0 + k);
    av[1] = *(const float4*)(arow1 + k);
    av[2] = *(const float4*)(arow2 + k);
    av[3] = *(const float4*)(arow3 + k);
#pragma unroll
    for (int kk=0;kk<4;++kk){
      float4 w0 = *(const float4*)(wp + (k+kk)*128);
      float4 w1 = *(const float4*)(wp + (k+kk)*128 + 4);
#pragma unroll
      for (int r=0;r<4;++r){
        float a = ((const float*)&av[r])[kk];
        acc[r][0] = fmaf(a,w0.x,acc[r][0]);
        acc[r][1] = fmaf(a,w0.y,acc[r][1]);
        acc[r][2] = fmaf(a,w0.z,acc[r][2]);
        acc[r][3] = fmaf(a,w0.w,acc[r][3]);
        acc[r][4] = fmaf(a,w1.x,acc[r][4]);
        acc[r][5] = fmaf(a,w1.y,acc[r][5]);
        acc[r][6] = fmaf(a,w1.z,acc[r][6]);
        acc[r][7] = fmaf(a,w1.w,acc[r][7]);
      }
    }
  }
  float bb[8];
  {
    float4 b0 = *(const float4*)(bias + 8*tc);
    float4 b1 = *(const float4*)(bias + 8*tc + 4);
    bb[0]=b0.x; bb[1]=b0.y; bb[2]=b0.z; bb[3]=b0.w;
    bb[4]=b1.x; bb[5]=b1.y; bb[6]=b1.z; bb[7]=b1.w;
  }
#pragma unroll
  for (int r=0;r<4;++r){
    float o[8];
#pragma unroll
    for (int c=0;c<8;++c){
      float v = acc[r][c] + bb[c];
      o[c] = DOTANH ? tanh_f(v) : v;
    }
    float* orow = Odst + (4*tr+r)*HPITCH + 8*tc;
    *(float4*)(orow)   = make_float4(o[0],o[1],o[2],o[3]);
    *(float4*)(orow+4) = make_float4(o[4],o[5],o[6],o[7]);
  }
}

// ---------- final a-layer: aug(64 x 256) = A(64 x 128) @ W(128 x 256) + b (no act), to global ----------
__device__ __forceinline__ void layer_out256(const float* __restrict__ Alds,
    const float* __restrict__ W, const float* __restrict__ bias,
    float* __restrict__ Og, int tr, int tc)
{
#pragma unroll 1
  for (int cb=0; cb<2; ++cb){            // two 128-wide col blocks to cap VGPRs
    const int col = cb*128 + 8*tc;
    float acc[4][8];
#pragma unroll
    for (int r=0;r<4;++r)
#pragma unroll
      for (int c=0;c<8;++c) acc[r][c]=0.0f;
    const float* wp = W + col;
#pragma unroll 2
    for (int k=0;k<128;k+=4){
      float4 av[4];
#pragma unroll
      for (int r=0;r<4;++r) av[r] = *(const float4*)(Alds + (4*tr+r)*HPITCH + k);
#pragma unroll
      for (int kk=0;kk<4;++kk){
        float4 w0 = *(const float4*)(wp + (k+kk)*256);
        float4 w1 = *(const float4*)(wp + (k+kk)*256 + 4);
#pragma unroll
        for (int r=0;r<4;++r){
          float a = ((const float*)&av[r])[kk];
          acc[r][0] = fmaf(a,w0.x,acc[r][0]);
          acc[r][1] = fmaf(a,w0.y,acc[r][1]);
          acc[r][2] = fmaf(a,w0.z,acc[r][2]);
          acc[r][3] = fmaf(a,w0.w,acc[r][3]);
          acc[r][4] = fmaf(a,w1.x,acc[r][4]);
          acc[r][5] = fmaf(a,w1.y,acc[r][5]);
          acc[r][6] = fmaf(a,w1.z,acc[r][6]);
          acc[r][7] = fmaf(a,w1.w,acc[r][7]);
        }
      }
    }
    float4 b0 = *(const float4*)(bias + col);
    float4 b1 = *(const float4*)(bias + col + 4);
#pragma unroll
    for (int r=0;r<4;++r){
      float* orow = Og + (4*tr+r)*256 + col;
      *(float4*)(orow)   = make_float4(acc[r][0]+b0.x, acc[r][1]+b0.y, acc[r][2]+b0.z, acc[r][3]+b0.w);
      *(float4*)(orow+4) = make_float4(acc[r][4]+b1.x, acc[r][5]+b1.y, acc[r][6]+b1.z, acc[r][7]+b1.w);
    }
  }
}

// ---------- final p-layer: frac(64 x 16) = sigmoid(A(64 x 128) @ W(128 x 16) + b), to global ----------
__device__ __forceinline__ void layer_out16(const float* __restrict__ Alds,
    const float* __restrict__ W, const float* __restrict__ bias,
    float* __restrict__ Og, int tr, int tc)
{
  float acc[4] = {0.f,0.f,0.f,0.f};
#pragma unroll 2
  for (int k=0;k<128;k+=4){
    float4 av[4];
#pragma unroll
    for (int r=0;r<4;++r) av[r] = *(const float4*)(Alds + (4*tr+r)*HPITCH + k);
#pragma unroll
    for (int kk=0;kk<4;++kk){
      float w = W[(k+kk)*16 + tc];
#pragma unroll
      for (int r=0;r<4;++r)
        acc[r] = fmaf(((const float*)&av[r])[kk], w, acc[r]);
    }
  }
  float b = bias[tc];
#pragma unroll
  for (int r=0;r<4;++r)
    Og[(4*tr+r)*16 + tc] = sigmoid_f(acc[r] + b);
}

// ================= Kernel 1: both MLPs =================
// grid NB/64 blocks x 256 threads. 64 rows/block. Weights come from global (L1/L2-resident).
__global__ __launch_bounds__(256, 2) void mlp_kernel(
  const float* __restrict__ bids,
  const float* __restrict__ aw0, const float* __restrict__ ab0,
  const float* __restrict__ aw1, const float* __restrict__ ab1,
  const float* __restrict__ aw2, const float* __restrict__ ab2,
  const float* __restrict__ aw3, const float* __restrict__ ab3,
  const float* __restrict__ pw0, const float* __restrict__ pb0,
  const float* __restrict__ pw1, const float* __restrict__ pb1,
  const float* __restrict__ pw2, const float* __restrict__ pb2,
  const float* __restrict__ pw3, const float* __restrict__ pb3,
  float* __restrict__ aug, float* __restrict__ fracv)
{
  __shared__ float bufA[64*HPITCH];
  __shared__ float bufB[64*HPITCH];
  const int tid = threadIdx.x;
  const int tc = tid & 15;
  const int tr = tid >> 4;
  const long row0 = (long)blockIdx.x * 64;
  const float* Xg = bids + row0 * 256;

  // allocation net
  layerN128<256,256,true>(Xg,   aw0, ab0, bufA, tr, tc);  __syncthreads();
  layerN128<128,HPITCH,true>(bufA, aw1, ab1, bufB, tr, tc); __syncthreads();
  layerN128<128,HPITCH,true>(bufB, aw2, ab2, bufA, tr, tc); __syncthreads();
  layer_out256(bufA, aw3, ab3, aug + row0*256, tr, tc);    __syncthreads();
  // payment net
  layerN128<256,256,true>(Xg,   pw0, pb0, bufB, tr, tc);  __syncthreads();
  layerN128<128,HPITCH,true>(bufB, pw1, pb1, bufA, tr, tc); __syncthreads();
  layerN128<128,HPITCH,true>(bufA, pw2, pb2, bufB, tr, tc); __syncthreads();
  layer_out16(bufB, pw3, pb3, fracv + row0*16, tr, tc);
}

// ================= Kernel 2: Sinkhorn + payments =================
// Linear-domain u/v Sinkhorn (exactly equivalent to reference's log-domain iteration;
// row-max pre-scaling is absorbed by the first u-update). 4 lanes per element: lane c
// owns cols 4c..4c+3 in registers; lane 3 also owns pad col 16. Row sums via quad shfl_xor.
__global__ __launch_bounds__(256, 2) void sinkhorn_kernel(
  const float* __restrict__ aug, const float* __restrict__ bids,
  const float* __restrict__ fracv, float* __restrict__ out)
{
  const int tid = threadIdx.x;
  const int c = tid & 3;
  const long e = (long)blockIdx.x * 64 + (tid >> 2);
  const float S = 14.426950408889634f;         // (1/EPS)/ln2 : logits in exp2 units
  const float cmask = (c == 3) ? 1.0f : 0.0f;

  float Kx[4][17];   // owned columns (4c+cc), rows 0..16 (row 16 = pad row, logit 0)
  float K16[17];     // pad column 16 (lane 3 only; zeroed elsewhere)

  const float* ap = aug + e*256 + 4*c;
#pragma unroll
  for (int i=0;i<16;++i){
    float4 v = *(const float4*)(ap + i*16);
    Kx[0][i]=v.x*S; Kx[1][i]=v.y*S; Kx[2][i]=v.z*S; Kx[3][i]=v.w*S;
  }
  Kx[0][16]=0.f; Kx[1][16]=0.f; Kx[2][16]=0.f; Kx[3][16]=0.f;

  float u[17];
  // row max (includes pad col's logit 0), then exponentiate
#pragma unroll
  for (int i=0;i<17;++i){
    float mm = fmaxf(fmaxf(Kx[0][i],Kx[1][i]), fmaxf(Kx[2][i],Kx[3][i]));
    mm = fmaxf(mm, 0.0f);
    mm = fmaxf(mm, __shfl_xor(mm, 1));
    mm = fmaxf(mm, __shfl_xor(mm, 2));
    Kx[0][i] = exp2_f(Kx[0][i]-mm);
    Kx[1][i] = exp2_f(Kx[1][i]-mm);
    Kx[2][i] = exp2_f(Kx[2][i]-mm);
    Kx[3][i] = exp2_f(Kx[3][i]-mm);
    K16[i]   = cmask * exp2_f(-mm);
  }

  float vj0=1.f, vj1=1.f, vj2=1.f, vj3=1.f;
  float v16 = cmask;

  for (int r=0;r<40;++r){
    // row pass: s_i = sum_j K_ij v_j  (quad butterfly), u_i = a_i / s_i
#pragma unroll
    for (int i=0;i<17;++i){
      float p = Kx[0][i]*vj0 + Kx[1][i]*vj1 + Kx[2][i]*vj2 + Kx[3][i]*vj3 + K16[i]*v16;
      p += __shfl_xor(p, 1);
      p += __shfl_xor(p, 2);
      u[i] = rcp_f(p);
    }
    u[16] *= 16.0f;   // a_16 = I = 16
    // col pass: t_j = sum_i K_ij u_i (lane-local), v_j = b_j / t_j
    float t0=0.f,t1=0.f,t2=0.f,t3=0.f,t16=0.f;
#pragma unroll
    for (int i=0;i<17;++i){
      t0  = fmaf(Kx[0][i],u[i],t0);
      t1  = fmaf(Kx[1][i],u[i],t1);
      t2  = fmaf(Kx[2][i],u[i],t2);
      t3  = fmaf(Kx[3][i],u[i],t3);
      t16 = fmaf(K16[i], u[i],t16);
    }
    vj0 = rcp_f(t0); vj1 = rcp_f(t1); vj2 = rcp_f(t2); vj3 = rcp_f(t3);
    v16 = cmask * 16.0f * rcp_f(t16 + 1e-30f + (1.0f - cmask));  // b_16 = A = 16; NaN-guard off-lane
  }

  // allocs = u_i * K_ij * v_j  (real 16x16 block)
  float* op = out + e*256 + 4*c;
#pragma unroll
  for (int i=0;i<16;++i){
    float4 w;
    w.x = u[i]*Kx[0][i]*vj0;
    w.y = u[i]*Kx[1][i]*vj1;
    w.z = u[i]*Kx[2][i]*vj2;
    w.w = u[i]*Kx[3][i]*vj3;
    *(float4*)(op + i*16) = w;
  }

  // payments_i = frac_i * sum_j allocs_ij * bids_ij
  const float* bp = bids + e*256 + 4*c;
  float pay[16];
#pragma unroll
  for (int i=0;i<16;++i){
    float4 bb = *(const float4*)(bp + i*16);
    float s = u[i]*(Kx[0][i]*vj0*bb.x + Kx[1][i]*vj1*bb.y + Kx[2][i]*vj2*bb.z + Kx[3][i]*vj3*bb.w);
    s += __shfl_xor(s, 1);
    s += __shfl_xor(s, 2);
    pay[i] = s;
  }
  float4 pv;
  if      (c==0) pv = make_float4(pay[0],pay[1],pay[2],pay[3]);
  else if (c==1) pv = make_float4(pay[4],pay[5],pay[6],pay[7]);
  else if (c==2) pv = make_float4(pay[8],pay[9],pay[10],pay[11]);
  else           pv = make_float4(pay[12],pay[13],pay[14],pay[15]);
  const float4 fr = *(const float4*)(fracv + e*16 + 4*c);
  pv.x *= fr.x; pv.y *= fr.y; pv.z *= fr.z; pv.w *= fr.w;
  *(float4*)(out + (size_t)NB*256 + e*16 + 4*c) = pv;
}

// ================= launch =================
extern "C" void kernel_launch(void* const* d_in, const int* in_sizes, int n_in,
                              void* d_out, int out_size, void* d_ws, size_t ws_size,
                              hipStream_t stream)
{
  const float* bids = (const float*)d_in[0];
  const float* aw0 = (const float*)d_in[1];
  const float* ab0 = (const float*)d_in[2];
  const float* aw1 = (const float*)d_in[3];
  const float* ab1 = (const float*)d_in[4];
  const float* aw2 = (const float*)d_in[5];
  const float* ab2 = (const float*)d_in[6];
  const float* aw3 = (const float*)d_in[7];
  const float* ab3 = (const float*)d_in[8];
  const float* pw0 = (const float*)d_in[9];
  const float* pb0 = (const float*)d_in[10];
  const float* pw1 = (const float*)d_in[11];
  const float* pb1 = (const float*)d_in[12];
  const float* pw2 = (const float*)d_in[13];
  const float* pb2 = (const float*)d_in[14];
  const float* pw3 = (const float*)d_in[15];
  const float* pb3 = (const float*)d_in[16];

  float* aug   = (float*)d_ws;                       // NB*256 floats
  float* fracv = aug + (size_t)NB*256;               // NB*16 floats

  dim3 grid(NB/64), block(256);
  mlp_kernel<<<grid, block, 0, stream>>>(bids, aw0,ab0,aw1,ab1,aw2,ab2,aw3,ab3,
                                         pw0,pb0,pw1,pb1,pw2,pb2,pw3,pb3, aug, fracv);
  sinkhorn_kernel<<<grid, block, 0, stream>>>(aug, bids, fracv, (float*)d_out);
}

// Round 3
// 280.107 us; speedup vs baseline: 1.2405x; 1.2405x over previous
//
#include <hip/hip_runtime.h>

#define NB 32768

typedef _Float16 half8 __attribute__((ext_vector_type(8)));
typedef float floatx4 __attribute__((ext_vector_type(4)));
typedef unsigned int uint4v __attribute__((ext_vector_type(4)));

#define MFMA16(a,b,c) __builtin_amdgcn_mfma_f32_16x16x32_f16(a,b,c,0,0,0)

// ---------- fast math ----------
__device__ __forceinline__ float rcp_f(float x){ return __builtin_amdgcn_rcpf(x); }
__device__ __forceinline__ float exp2_f(float x){ return __builtin_amdgcn_exp2f(x); }
__device__ __forceinline__ float tanh_f(float x){
  float e = exp2_f(x * 2.8853900817779268f);     // e^(2x)
  return (e - 1.0f) * rcp_f(e + 1.0f);
}
__device__ __forceinline__ float sigmoid_f(float x){
  return rcp_f(1.0f + exp2_f(-1.4426950408889634f * x));
}

// DPP quad butterflies (within each quad): xor1 = quad_perm[1,0,3,2]=0xB1, xor2 = [2,3,0,1]=0x4E
template<int CTRL>
__device__ __forceinline__ float dpp_qp(float x){
  return __builtin_bit_cast(float, __builtin_amdgcn_update_dpp(0, __builtin_bit_cast(int,x), CTRL, 0xF, 0xF, true));
}
__device__ __forceinline__ float qadd2(float x){
  x += dpp_qp<0xB1>(x);
  x += dpp_qp<0x4E>(x);
  return x;
}
__device__ __forceinline__ float qmax2(float x){
  x = fmaxf(x, dpp_qp<0xB1>(x));
  x = fmaxf(x, dpp_qp<0x4E>(x));
  return x;
}

// ---------- f16 weight region offsets (in _Float16 units), lives in d_out payments tail ----------
// layout Wt[n][k] (n-major, contiguous k) for MFMA B-fragment 16B loads
constexpr int O_AW0H = 0;        // 256x128
constexpr int O_AW1H = 32768;    // 128x128
constexpr int O_AW2H = 49152;
constexpr int O_AW3H = 65536;    // 128x256
constexpr int O_PW0H = 98304;
constexpr int O_PW1H = 131072;
constexpr int O_PW2H = 147456;
constexpr int O_PW3H = 163840;   // 128x16
constexpr int O_AW1L = 165888;
constexpr int O_AW2L = 182272;
constexpr int O_AW3L = 198656;
constexpr int O_WTOT = 231424;   // * 2B = 452 KB < 2 MB payments region

// ---------- weight prep: transpose + split f32 -> f16 hi/lo ----------
struct PrepJob { const float* src; _Float16* h; _Float16* l; int kshift; int total; };
struct PrepJobs { PrepJob j[8]; };

__global__ void prep_kernel(PrepJobs js){
  const PrepJob jb = js.j[blockIdx.y];
  const int idx = blockIdx.x*256 + threadIdx.x;
  if (idx >= jb.total) return;
  const int K = 1 << jb.kshift;
  const int n = idx >> jb.kshift;
  const int k = idx & (K-1);
  const int N = jb.total >> jb.kshift;
  float w = jb.src[(long)k*N + n];
  _Float16 h = (_Float16)w;
  jb.h[idx] = h;
  if (jb.l) jb.l[idx] = (_Float16)(w - (float)h);
}

// ---------- LDS activation layout: 64 rows x 128 cols of packed (hi|lo) u32 ----------
// 16B-chunk XOR swizzle by (row&7): bank-conflict-free A-frag reads & ~2-way writes
__device__ __forceinline__ int aaddr(int row, int col){
  int cc = (col >> 2) ^ (row & 7);
  return row*128 + (cc<<2) + (col & 3);
}

template<bool NEED_LO>
__device__ __forceinline__ void read_frag(const unsigned int* __restrict__ act,
    int row, int ks, int q, half8& ah, half8& al)
{
  const int s = row & 7;
  const int cc0 = ks*8 + q*2;
  uint4v c0 = *(const uint4v*)(act + row*128 + (((cc0  ) ^ s)<<2));
  uint4v c1 = *(const uint4v*)(act + row*128 + (((cc0+1) ^ s)<<2));
  uint4v h;
  h.x = (c0.x & 0xffffu) | (c0.y << 16);
  h.y = (c0.z & 0xffffu) | (c0.w << 16);
  h.z = (c1.x & 0xffffu) | (c1.y << 16);
  h.w = (c1.z & 0xffffu) | (c1.w << 16);
  ah = __builtin_bit_cast(half8, h);
  if constexpr (NEED_LO){
    uint4v g;
    g.x = (c0.x >> 16) | (c0.y & 0xffff0000u);
    g.y = (c0.z >> 16) | (c0.w & 0xffff0000u);
    g.z = (c1.x >> 16) | (c1.y & 0xffff0000u);
    g.w = (c1.z >> 16) | (c1.w & 0xffff0000u);
    al = __builtin_bit_cast(half8, g);
  }
}

__device__ __forceinline__ unsigned int pack_act(float v){
  _Float16 h = (_Float16)v;
  _Float16 lo = (_Float16)(v - (float)h);
  return (unsigned int)__builtin_bit_cast(unsigned short, h)
       | ((unsigned int)__builtin_bit_cast(unsigned short, lo) << 16);
}

__device__ __forceinline__ half8 load_xfrag(const float* __restrict__ X, long row, int k0){
  float4 a = *(const float4*)(X + row*256 + k0);
  float4 b = *(const float4*)(X + row*256 + k0 + 4);
  half8 h;
  h[0]=(_Float16)a.x; h[1]=(_Float16)a.y; h[2]=(_Float16)a.z; h[3]=(_Float16)a.w;
  h[4]=(_Float16)b.x; h[5]=(_Float16)b.y; h[6]=(_Float16)b.z; h[7]=(_Float16)b.w;
  return h;
}

// ---------- MFMA inner block: 2 m-tiles x NT n-tiles, K = KS*32 ----------
template<int KS, int PASSES, int NT>
__device__ __forceinline__ void mfma_block(
    const half8 Ah[2][KS], const half8 Al[2][KS],
    const _Float16* __restrict__ Wh, const _Float16* __restrict__ Wl,
    int K, int l15, int q, floatx4 acc[NT][2])
{
#pragma unroll
  for (int nt=0; nt<NT; ++nt){
    const _Float16* bp = Wh + (nt*16 + l15)*K + q*8;
#pragma unroll
    for (int ks=0; ks<KS; ++ks){
      half8 bh = *(const half8*)(bp + ks*32);
      acc[nt][0] = MFMA16(Ah[0][ks], bh, acc[nt][0]);
      acc[nt][1] = MFMA16(Ah[1][ks], bh, acc[nt][1]);
      if constexpr (PASSES == 3){
        const _Float16* blp = Wl + (nt*16 + l15)*K + q*8;
        half8 bl = *(const half8*)(blp + ks*32);
        acc[nt][0] = MFMA16(Al[0][ks], bh, acc[nt][0]);
        acc[nt][1] = MFMA16(Al[1][ks], bh, acc[nt][1]);
        acc[nt][0] = MFMA16(Ah[0][ks], bl, acc[nt][0]);
        acc[nt][1] = MFMA16(Ah[1][ks], bl, acc[nt][1]);
      }
    }
  }
}

__device__ __forceinline__ void epi_tanh(floatx4 acc[8][2], const float* __restrict__ bias,
    unsigned int* __restrict__ act, int wv, int q, int l15)
{
#pragma unroll
  for (int nt=0; nt<8; ++nt){
    float bb = bias[nt*16 + l15];
#pragma unroll
    for (int mt=0; mt<2; ++mt)
#pragma unroll
      for (int r=0; r<4; ++r){
        float t = tanh_f(acc[nt][mt][r] + bb);
        act[aaddr(wv*32 + mt*16 + q*4 + r, nt*16 + l15)] = pack_act(t);
      }
  }
}

template<int PASSES>
__device__ __forceinline__ void hidden128(unsigned int* __restrict__ act,
    const _Float16* __restrict__ Wh, const _Float16* __restrict__ Wl,
    const float* __restrict__ bias, int wv, int q, int l15)
{
  half8 Ah[2][4], Al[2][4];
#pragma unroll
  for (int mt=0; mt<2; ++mt)
#pragma unroll
    for (int ks=0; ks<4; ++ks)
      read_frag<PASSES==3>(act, wv*32 + mt*16 + l15, ks, q, Ah[mt][ks], Al[mt][ks]);
  floatx4 acc[8][2];
#pragma unroll
  for (int nt=0; nt<8; ++nt){ acc[nt][0] = (floatx4)0.0f; acc[nt][1] = (floatx4)0.0f; }
  mfma_block<4,PASSES,8>(Ah, Al, Wh, Wl, 128, l15, q, acc);
  epi_tanh(acc, bias, act, wv, q, l15);
}

// ================= Kernel: both MLPs via f16 MFMA =================
// block = 128 threads (2 waves), 64 rows/block; wave owns 32 rows (2 m-tiles) -> no inter-wave LDS sharing, no barriers
__global__ __launch_bounds__(128, 2) void mlp_mfma(
  const float* __restrict__ X, const _Float16* __restrict__ WT,
  const float* __restrict__ ab0, const float* __restrict__ ab1,
  const float* __restrict__ ab2, const float* __restrict__ ab3,
  const float* __restrict__ pb0, const float* __restrict__ pb1,
  const float* __restrict__ pb2, const float* __restrict__ pb3,
  float* __restrict__ aug, float* __restrict__ fracv)
{
  __shared__ unsigned int act[64*128];   // 32 KB
  const int tid = threadIdx.x, wv = tid>>6, l = tid&63, q = l>>4, l15 = l&15;
  const long rb = (long)blockIdx.x * 64;

  // ---- a-net L1 (K=256, 1-pass: noise decays through 3 tanh layers) ----
  {
    half8 Xf[2][8];
#pragma unroll
    for (int mt=0; mt<2; ++mt)
#pragma unroll
      for (int ks=0; ks<8; ++ks)
        Xf[mt][ks] = load_xfrag(X, rb + wv*32 + mt*16 + l15, ks*32 + q*8);
    floatx4 acc[8][2];
#pragma unroll
    for (int nt=0; nt<8; ++nt){ acc[nt][0] = (floatx4)0.0f; acc[nt][1] = (floatx4)0.0f; }
    mfma_block<8,1,8>(Xf, Xf, WT+O_AW0H, WT+O_AW0H, 256, l15, q, acc);
    epi_tanh(acc, ab0, act, wv, q, l15);
  }
  // ---- a-net L2,L3: split-corrected (3-pass ~= fp32 exact) ----
  hidden128<3>(act, WT+O_AW1H, WT+O_AW1L, ab1, wv, q, l15);
  hidden128<3>(act, WT+O_AW2H, WT+O_AW2L, ab2, wv, q, l15);
  // ---- a-net L4 -> aug (f32, no activation), split-corrected ----
  {
    half8 Ah[2][4], Al[2][4];
#pragma unroll
    for (int mt=0; mt<2; ++mt)
#pragma unroll
      for (int ks=0; ks<4; ++ks)
        read_frag<true>(act, wv*32 + mt*16 + l15, ks, q, Ah[mt][ks], Al[mt][ks]);
#pragma unroll
    for (int hf=0; hf<2; ++hf){
      floatx4 acc[8][2];
#pragma unroll
      for (int nt=0; nt<8; ++nt){ acc[nt][0] = (floatx4)0.0f; acc[nt][1] = (floatx4)0.0f; }
      mfma_block<4,3,8>(Ah, Al, WT+O_AW3H + hf*128*128, WT+O_AW3L + hf*128*128, 128, l15, q, acc);
      const int ncol0 = hf*128;
#pragma unroll
      for (int nt=0; nt<8; ++nt){
        float bb = ab3[ncol0 + nt*16 + l15];
#pragma unroll
        for (int mt=0; mt<2; ++mt)
#pragma unroll
          for (int r=0; r<4; ++r)
            aug[(rb + wv*32 + mt*16 + q*4 + r)*256 + ncol0 + nt*16 + l15] = acc[nt][mt][r] + bb;
      }
    }
  }
  // ---- p-net (1-pass f16: payments tolerance is lenient) ----
  {
    half8 Xf[2][8];
#pragma unroll
    for (int mt=0; mt<2; ++mt)
#pragma unroll
      for (int ks=0; ks<8; ++ks)
        Xf[mt][ks] = load_xfrag(X, rb + wv*32 + mt*16 + l15, ks*32 + q*8);
    floatx4 acc[8][2];
#pragma unroll
    for (int nt=0; nt<8; ++nt){ acc[nt][0] = (floatx4)0.0f; acc[nt][1] = (floatx4)0.0f; }
    mfma_block<8,1,8>(Xf, Xf, WT+O_PW0H, WT+O_PW0H, 256, l15, q, acc);
    epi_tanh(acc, pb0, act, wv, q, l15);
  }
  hidden128<1>(act, WT+O_PW1H, WT+O_PW1H, pb1, wv, q, l15);
  hidden128<1>(act, WT+O_PW2H, WT+O_PW2H, pb2, wv, q, l15);
  // ---- p-net L4 -> frac (sigmoid), N=16 ----
  {
    half8 Ah[2][4], Al[2][4];
#pragma unroll
    for (int mt=0; mt<2; ++mt)
#pragma unroll
      for (int ks=0; ks<4; ++ks)
        read_frag<false>(act, wv*32 + mt*16 + l15, ks, q, Ah[mt][ks], Al[mt][ks]);
    floatx4 acc[1][2];
    acc[0][0] = (floatx4)0.0f; acc[0][1] = (floatx4)0.0f;
    mfma_block<4,1,1>(Ah, Al, WT+O_PW3H, WT+O_PW3H, 128, l15, q, acc);
    float bb = pb3[l15];
#pragma unroll
    for (int mt=0; mt<2; ++mt)
#pragma unroll
      for (int r=0; r<4; ++r)
        fracv[(rb + wv*32 + mt*16 + q*4 + r)*16 + l15] = sigmoid_f(acc[0][mt][r] + bb);
  }
}

// ================= Kernel: Sinkhorn + payments (DPP cross-lane) =================
__global__ __launch_bounds__(256, 2) void sinkhorn_kernel(
  const float* __restrict__ aug, const float* __restrict__ bids,
  const float* __restrict__ fracv, float* __restrict__ out)
{
  const int tid = threadIdx.x;
  const int c = tid & 3;
  const long e = (long)blockIdx.x * 64 + (tid >> 2);
  const float S = 14.426950408889634f;         // (1/EPS)/ln2 : logits in exp2 units
  const float cmask = (c == 3) ? 1.0f : 0.0f;

  float Kx[4][17];   // owned columns (4c+cc), rows 0..16 (row 16 = pad row, logit 0)
  float K16[17];     // pad column 16 (lane 3 only; zeroed elsewhere)

  const float* ap = aug + e*256 + 4*c;
#pragma unroll
  for (int i=0;i<16;++i){
    float4 v = *(const float4*)(ap + i*16);
    Kx[0][i]=v.x*S; Kx[1][i]=v.y*S; Kx[2][i]=v.z*S; Kx[3][i]=v.w*S;
  }
  Kx[0][16]=0.f; Kx[1][16]=0.f; Kx[2][16]=0.f; Kx[3][16]=0.f;

  float u[17];
#pragma unroll
  for (int i=0;i<17;++i){
    float mm = fmaxf(fmaxf(Kx[0][i],Kx[1][i]), fmaxf(Kx[2][i],Kx[3][i]));
    mm = fmaxf(mm, 0.0f);
    mm = qmax2(mm);
    Kx[0][i] = exp2_f(Kx[0][i]-mm);
    Kx[1][i] = exp2_f(Kx[1][i]-mm);
    Kx[2][i] = exp2_f(Kx[2][i]-mm);
    Kx[3][i] = exp2_f(Kx[3][i]-mm);
    K16[i]   = cmask * exp2_f(-mm);
  }

  float vj0=1.f, vj1=1.f, vj2=1.f, vj3=1.f;
  float v16 = cmask;

  for (int r=0;r<40;++r){
#pragma unroll
    for (int i=0;i<17;++i){
      float p = Kx[0][i]*vj0 + Kx[1][i]*vj1 + Kx[2][i]*vj2 + Kx[3][i]*vj3 + K16[i]*v16;
      p = qadd2(p);
      u[i] = rcp_f(p);
    }
    u[16] *= 16.0f;   // a_16 = I = 16
    float t0=0.f,t1=0.f,t2=0.f,t3=0.f,t16=0.f;
#pragma unroll
    for (int i=0;i<17;++i){
      t0  = fmaf(Kx[0][i],u[i],t0);
      t1  = fmaf(Kx[1][i],u[i],t1);
      t2  = fmaf(Kx[2][i],u[i],t2);
      t3  = fmaf(Kx[3][i],u[i],t3);
      t16 = fmaf(K16[i], u[i],t16);
    }
    vj0 = rcp_f(t0); vj1 = rcp_f(t1); vj2 = rcp_f(t2); vj3 = rcp_f(t3);
    v16 = cmask * 16.0f * rcp_f(t16 + 1e-30f + (1.0f - cmask));  // b_16 = A = 16; NaN-guard off-lane
  }

  float* op = out + e*256 + 4*c;
#pragma unroll
  for (int i=0;i<16;++i){
    float4 w;
    w.x = u[i]*Kx[0][i]*vj0;
    w.y = u[i]*Kx[1][i]*vj1;
    w.z = u[i]*Kx[2][i]*vj2;
    w.w = u[i]*Kx[3][i]*vj3;
    *(float4*)(op + i*16) = w;
  }

  const float* bp = bids + e*256 + 4*c;
  float pay[16];
#pragma unroll
  for (int i=0;i<16;++i){
    float4 bb = *(const float4*)(bp + i*16);
    float s = u[i]*(Kx[0][i]*vj0*bb.x + Kx[1][i]*vj1*bb.y + Kx[2][i]*vj2*bb.z + Kx[3][i]*vj3*bb.w);
    pay[i] = qadd2(s);
  }
  float4 pv;
  if      (c==0) pv = make_float4(pay[0],pay[1],pay[2],pay[3]);
  else if (c==1) pv = make_float4(pay[4],pay[5],pay[6],pay[7]);
  else if (c==2) pv = make_float4(pay[8],pay[9],pay[10],pay[11]);
  else           pv = make_float4(pay[12],pay[13],pay[14],pay[15]);
  const float4 fr = *(const float4*)(fracv + e*16 + 4*c);
  pv.x *= fr.x; pv.y *= fr.y; pv.z *= fr.z; pv.w *= fr.w;
  *(float4*)(out + (size_t)NB*256 + e*16 + 4*c) = pv;
}

// ================= launch =================
extern "C" void kernel_launch(void* const* d_in, const int* in_sizes, int n_in,
                              void* d_out, int out_size, void* d_ws, size_t ws_size,
                              hipStream_t stream)
{
  const float* bids = (const float*)d_in[0];
  const float* aw0 = (const float*)d_in[1];  const float* ab0 = (const float*)d_in[2];
  const float* aw1 = (const float*)d_in[3];  const float* ab1 = (const float*)d_in[4];
  const float* aw2 = (const float*)d_in[5];  const float* ab2 = (const float*)d_in[6];
  const float* aw3 = (const float*)d_in[7];  const float* ab3 = (const float*)d_in[8];
  const float* pw0 = (const float*)d_in[9];  const float* pb0 = (const float*)d_in[10];
  const float* pw1 = (const float*)d_in[11]; const float* pb1 = (const float*)d_in[12];
  const float* pw2 = (const float*)d_in[13]; const float* pb2 = (const float*)d_in[14];
  const float* pw3 = (const float*)d_in[15]; const float* pb3 = (const float*)d_in[16];

  float* aug   = (float*)d_ws;                       // NB*256 f32
  float* fracv = aug + (size_t)NB*256;               // NB*16 f32

  // f16 transposed/split weights live in d_out's payments region (overwritten by sinkhorn at the very end,
  // after mlp_mfma has consumed them — stream-ordered, graph-capture safe)
  _Float16* WT = (_Float16*)((float*)d_out + (size_t)NB*256);

  PrepJobs js;
  js.j[0] = { aw0, WT+O_AW0H, nullptr,    8, 32768 };
  js.j[1] = { aw1, WT+O_AW1H, WT+O_AW1L,  7, 16384 };
  js.j[2] = { aw2, WT+O_AW2H, WT+O_AW2L,  7, 16384 };
  js.j[3] = { aw3, WT+O_AW3H, WT+O_AW3L,  7, 32768 };
  js.j[4] = { pw0, WT+O_PW0H, nullptr,    8, 32768 };
  js.j[5] = { pw1, WT+O_PW1H, nullptr,    7, 16384 };
  js.j[6] = { pw2, WT+O_PW2H, nullptr,    7, 16384 };
  js.j[7] = { pw3, WT+O_PW3H, nullptr,    7, 2048  };

  prep_kernel<<<dim3(128,8), 256, 0, stream>>>(js);
  mlp_mfma<<<dim3(NB/64), 128, 0, stream>>>(bids, WT, ab0,ab1,ab2,ab3, pb0,pb1,pb2,pb3, aug, fracv);
  sinkhorn_kernel<<<dim3(NB/64), 256, 0, stream>>>(aug, bids, fracv, (float*)d_out);
}

// Round 4
// 262.914 us; speedup vs baseline: 1.3216x; 1.0654x over previous
//
#include <hip/hip_runtime.h>

#define NB 32768

typedef _Float16 half8 __attribute__((ext_vector_type(8)));
typedef float floatx4 __attribute__((ext_vector_type(4)));
typedef unsigned int uint4v __attribute__((ext_vector_type(4)));

#define MFMA16(a,b,c) __builtin_amdgcn_mfma_f32_16x16x32_f16(a,b,c,0,0,0)

// ---------- fast math ----------
__device__ __forceinline__ float rcp_f(float x){ return __builtin_amdgcn_rcpf(x); }
__device__ __forceinline__ float exp2_f(float x){ return __builtin_amdgcn_exp2f(x); }
__device__ __forceinline__ float tanh_f(float x){
  float e = exp2_f(x * 2.8853900817779268f);     // e^(2x)
  return (e - 1.0f) * rcp_f(e + 1.0f);
}
__device__ __forceinline__ float sigmoid_f(float x){
  return rcp_f(1.0f + exp2_f(-1.4426950408889634f * x));
}

// DPP quad butterflies: xor1 = quad_perm[1,0,3,2]=0xB1, xor2 = [2,3,0,1]=0x4E
template<int CTRL>
__device__ __forceinline__ float dpp_qp(float x){
  return __builtin_bit_cast(float, __builtin_amdgcn_update_dpp(0, __builtin_bit_cast(int,x), CTRL, 0xF, 0xF, true));
}
__device__ __forceinline__ float qadd2(float x){
  x += dpp_qp<0xB1>(x);
  x += dpp_qp<0x4E>(x);
  return x;
}
__device__ __forceinline__ float qmax2(float x){
  x = fmaxf(x, dpp_qp<0xB1>(x));
  x = fmaxf(x, dpp_qp<0x4E>(x));
  return x;
}

// ---------- f16 weight region offsets (in _Float16 units), lives in d_out payments tail ----------
constexpr int O_AW0H = 0;        // 256x128
constexpr int O_AW1H = 32768;    // 128x128
constexpr int O_AW2H = 49152;
constexpr int O_AW3H = 65536;    // 128x256
constexpr int O_PW0H = 98304;
constexpr int O_PW1H = 131072;
constexpr int O_PW2H = 147456;
constexpr int O_PW3H = 163840;   // 128x16
constexpr int O_AW1L = 165888;
constexpr int O_AW2L = 182272;
constexpr int O_AW3L = 198656;

// ---------- weight prep: transpose + split f32 -> f16 hi/lo ----------
struct PrepJob { const float* src; _Float16* h; _Float16* l; int kshift; int total; };
struct PrepJobs { PrepJob j[8]; };

__global__ void prep_kernel(PrepJobs js){
  const PrepJob jb = js.j[blockIdx.y];
  const int idx = blockIdx.x*256 + threadIdx.x;
  if (idx >= jb.total) return;
  const int K = 1 << jb.kshift;
  const int n = idx >> jb.kshift;
  const int k = idx & (K-1);
  const int N = jb.total >> jb.kshift;
  float w = jb.src[(long)k*N + n];
  _Float16 h = (_Float16)w;
  jb.h[idx] = h;
  if (jb.l) jb.l[idx] = (_Float16)(w - (float)h);
}

// ---------- LDS activation layout: 32 rows x 128 cols of packed (hi|lo) u32 ----------
// 16B-chunk XOR swizzle by (row&7)
__device__ __forceinline__ int aaddr(int row, int col){
  int cc = (col >> 2) ^ (row & 7);
  return row*128 + (cc<<2) + (col & 3);
}

template<bool NEED_LO>
__device__ __forceinline__ void read_frag(const unsigned int* __restrict__ act,
    int row, int ks, int q, half8& ah, half8& al)
{
  const int s = row & 7;
  const int cc0 = ks*8 + q*2;
  uint4v c0 = *(const uint4v*)(act + row*128 + (((cc0  ) ^ s)<<2));
  uint4v c1 = *(const uint4v*)(act + row*128 + (((cc0+1) ^ s)<<2));
  uint4v h;
  h.x = (c0.x & 0xffffu) | (c0.y << 16);
  h.y = (c0.z & 0xffffu) | (c0.w << 16);
  h.z = (c1.x & 0xffffu) | (c1.y << 16);
  h.w = (c1.z & 0xffffu) | (c1.w << 16);
  ah = __builtin_bit_cast(half8, h);
  if constexpr (NEED_LO){
    uint4v g;
    g.x = (c0.x >> 16) | (c0.y & 0xffff0000u);
    g.y = (c0.z >> 16) | (c0.w & 0xffff0000u);
    g.z = (c1.x >> 16) | (c1.y & 0xffff0000u);
    g.w = (c1.z >> 16) | (c1.w & 0xffff0000u);
    al = __builtin_bit_cast(half8, g);
  }
}

__device__ __forceinline__ unsigned int pack_act(float v){
  _Float16 h = (_Float16)v;
  _Float16 lo = (_Float16)(v - (float)h);
  return (unsigned int)__builtin_bit_cast(unsigned short, h)
       | ((unsigned int)__builtin_bit_cast(unsigned short, lo) << 16);
}

__device__ __forceinline__ half8 load_xfrag(const float* __restrict__ X, long row, int k0){
  float4 a = *(const float4*)(X + row*256 + k0);
  float4 b = *(const float4*)(X + row*256 + k0 + 4);
  half8 h;
  h[0]=(_Float16)a.x; h[1]=(_Float16)a.y; h[2]=(_Float16)a.z; h[3]=(_Float16)a.w;
  h[4]=(_Float16)b.x; h[5]=(_Float16)b.y; h[6]=(_Float16)b.z; h[7]=(_Float16)b.w;
  return h;
}

// ---------- MFMA inner block: 1 m-tile x NT n-tiles, K = KS*32 ----------
template<int KS, int PASSES, int NT>
__device__ __forceinline__ void mfma_block(
    const half8* Ah, const half8* Al,
    const _Float16* __restrict__ Wh, const _Float16* __restrict__ Wl,
    int K, int l15, int q, floatx4* acc)
{
#pragma unroll
  for (int nt=0; nt<NT; ++nt){
    const _Float16* bp = Wh + (nt*16 + l15)*K + q*8;
#pragma unroll
    for (int ks=0; ks<KS; ++ks){
      half8 bh = *(const half8*)(bp + ks*32);
      acc[nt] = MFMA16(Ah[ks], bh, acc[nt]);
      if constexpr (PASSES == 3){
        const _Float16* blp = Wl + (nt*16 + l15)*K + q*8;
        half8 bl = *(const half8*)(blp + ks*32);
        acc[nt] = MFMA16(Al[ks], bh, acc[nt]);
        acc[nt] = MFMA16(Ah[ks], bl, acc[nt]);
      }
    }
  }
}

// epilogue: bias+tanh+pack to LDS; rows wv*16 + q*4 + r
__device__ __forceinline__ void epi_tanh(floatx4* acc, const float* __restrict__ bias,
    unsigned int* __restrict__ act, int wv, int q, int l15)
{
#pragma unroll
  for (int nt=0; nt<8; ++nt){
    float bb = bias[nt*16 + l15];
#pragma unroll
    for (int r=0; r<4; ++r){
      float t = tanh_f(acc[nt][r] + bb);
      act[aaddr(wv*16 + q*4 + r, nt*16 + l15)] = pack_act(t);
    }
  }
}

template<int PASSES>
__device__ __forceinline__ void hidden128(unsigned int* __restrict__ act,
    const _Float16* __restrict__ Wh, const _Float16* __restrict__ Wl,
    const float* __restrict__ bias, int wv, int q, int l15)
{
  half8 Ah[4], Al[4];
#pragma unroll
  for (int ks=0; ks<4; ++ks)
    read_frag<PASSES==3>(act, wv*16 + l15, ks, q, Ah[ks], Al[ks]);
  floatx4 acc[8];
#pragma unroll
  for (int nt=0; nt<8; ++nt) acc[nt] = (floatx4)0.0f;
  mfma_block<4,PASSES,8>(Ah, Al, Wh, Wl, 128, l15, q, acc);
  epi_tanh(acc, bias, act, wv, q, l15);
}

// ================= Kernel: both MLPs via f16 MFMA =================
// block = 128 threads (2 waves), 32 rows/block; wave owns 16 rows (1 m-tile).
// a-net and p-net interleaved (independent chains) for latency overlap; X loaded once.
__global__ __launch_bounds__(128, 2) void mlp_mfma(
  const float* __restrict__ X, const _Float16* __restrict__ WT,
  const float* __restrict__ ab0, const float* __restrict__ ab1,
  const float* __restrict__ ab2, const float* __restrict__ ab3,
  const float* __restrict__ pb0, const float* __restrict__ pb1,
  const float* __restrict__ pb2, const float* __restrict__ pb3,
  float* __restrict__ aug, float* __restrict__ fracv)
{
  __shared__ unsigned int act_a[32*128];   // 16 KB
  __shared__ unsigned int act_p[32*128];   // 16 KB
  const int tid = threadIdx.x, wv = tid>>6, l = tid&63, q = l>>4, l15 = l&15;
  const long rb = (long)blockIdx.x * 32;

  // ---- L1 of both nets from one X fragment set (K=256) ----
  {
    half8 Xf[8];
#pragma unroll
    for (int ks=0; ks<8; ++ks)
      Xf[ks] = load_xfrag(X, rb + wv*16 + l15, ks*32 + q*8);
    floatx4 acca[8], accp[8];
#pragma unroll
    for (int nt=0; nt<8; ++nt){ acca[nt] = (floatx4)0.0f; accp[nt] = (floatx4)0.0f; }
    mfma_block<8,1,8>(Xf, Xf, WT+O_AW0H, WT+O_AW0H, 256, l15, q, acca);
    mfma_block<8,1,8>(Xf, Xf, WT+O_PW0H, WT+O_PW0H, 256, l15, q, accp);
    epi_tanh(acca, ab0, act_a, wv, q, l15);
    epi_tanh(accp, pb0, act_p, wv, q, l15);
  }
  // ---- hidden layers interleaved: a (3-pass split-corrected), p (1-pass) ----
  hidden128<3>(act_a, WT+O_AW1H, WT+O_AW1L, ab1, wv, q, l15);
  hidden128<1>(act_p, WT+O_PW1H, WT+O_PW1H, pb1, wv, q, l15);
  hidden128<3>(act_a, WT+O_AW2H, WT+O_AW2L, ab2, wv, q, l15);
  hidden128<1>(act_p, WT+O_PW2H, WT+O_PW2H, pb2, wv, q, l15);

  // ---- a-net L4 -> aug (f32, no activation), split-corrected ----
  {
    half8 Ah[4], Al[4];
#pragma unroll
    for (int ks=0; ks<4; ++ks)
      read_frag<true>(act_a, wv*16 + l15, ks, q, Ah[ks], Al[ks]);
#pragma unroll
    for (int hf=0; hf<2; ++hf){
      floatx4 acc[8];
#pragma unroll
      for (int nt=0; nt<8; ++nt) acc[nt] = (floatx4)0.0f;
      mfma_block<4,3,8>(Ah, Al, WT+O_AW3H + hf*128*128, WT+O_AW3L + hf*128*128, 128, l15, q, acc);
      const int ncol0 = hf*128;
#pragma unroll
      for (int nt=0; nt<8; ++nt){
        float bb = ab3[ncol0 + nt*16 + l15];
#pragma unroll
        for (int r=0; r<4; ++r)
          aug[(rb + wv*16 + q*4 + r)*256 + ncol0 + nt*16 + l15] = acc[nt][r] + bb;
      }
    }
  }
  // ---- p-net L4 -> frac (sigmoid), N=16 ----
  {
    half8 Ah[4], Al[4];
#pragma unroll
    for (int ks=0; ks<4; ++ks)
      read_frag<false>(act_p, wv*16 + l15, ks, q, Ah[ks], Al[ks]);
    floatx4 acc[1];
    acc[0] = (floatx4)0.0f;
    mfma_block<4,1,1>(Ah, Ah, WT+O_PW3H, WT+O_PW3H, 128, l15, q, acc);
    float bb = pb3[l15];
#pragma unroll
    for (int r=0; r<4; ++r)
      fracv[(rb + wv*16 + q*4 + r)*16 + l15] = sigmoid_f(acc[0][r] + bb);
  }
}

// ================= Kernel: Sinkhorn + payments (DPP cross-lane) =================
// launch_bounds (256,1): allow ~150 VGPRs so Kx[4][17]+u[17] stay in registers (no scratch)
__global__ __launch_bounds__(256, 1) void sinkhorn_kernel(
  const float* __restrict__ aug, const float* __restrict__ bids,
  const float* __restrict__ fracv, float* __restrict__ out)
{
  const int tid = threadIdx.x;
  const int c = tid & 3;
  const long e = (long)blockIdx.x * 64 + (tid >> 2);
  const float S = 14.426950408889634f;         // (1/EPS)/ln2 : logits in exp2 units
  const float cmask = (c == 3) ? 1.0f : 0.0f;

  float Kx[4][17];   // owned columns (4c+cc), rows 0..16 (row 16 = pad row, logit 0)
  float K16[17];     // pad column 16 (lane 3 only; zeroed elsewhere)

  const float* ap = aug + e*256 + 4*c;
#pragma unroll
  for (int i=0;i<16;++i){
    float4 v = *(const float4*)(ap + i*16);
    Kx[0][i]=v.x*S; Kx[1][i]=v.y*S; Kx[2][i]=v.z*S; Kx[3][i]=v.w*S;
  }
  Kx[0][16]=0.f; Kx[1][16]=0.f; Kx[2][16]=0.f; Kx[3][16]=0.f;

  float u[17];
#pragma unroll
  for (int i=0;i<17;++i){
    float mm = fmaxf(fmaxf(Kx[0][i],Kx[1][i]), fmaxf(Kx[2][i],Kx[3][i]));
    mm = fmaxf(mm, 0.0f);
    mm = qmax2(mm);
    Kx[0][i] = exp2_f(Kx[0][i]-mm);
    Kx[1][i] = exp2_f(Kx[1][i]-mm);
    Kx[2][i] = exp2_f(Kx[2][i]-mm);
    Kx[3][i] = exp2_f(Kx[3][i]-mm);
    K16[i]   = cmask * exp2_f(-mm);
  }

  float vj0=1.f, vj1=1.f, vj2=1.f, vj3=1.f;
  float v16 = cmask;

  for (int r=0;r<40;++r){
#pragma unroll
    for (int i=0;i<17;++i){
      float p = Kx[0][i]*vj0 + Kx[1][i]*vj1 + Kx[2][i]*vj2 + Kx[3][i]*vj3 + K16[i]*v16;
      p = qadd2(p);
      u[i] = rcp_f(p);
    }
    u[16] *= 16.0f;   // a_16 = I = 16
    float t0=0.f,t1=0.f,t2=0.f,t3=0.f,t16=0.f;
#pragma unroll
    for (int i=0;i<17;++i){
      t0  = fmaf(Kx[0][i],u[i],t0);
      t1  = fmaf(Kx[1][i],u[i],t1);
      t2  = fmaf(Kx[2][i],u[i],t2);
      t3  = fmaf(Kx[3][i],u[i],t3);
      t16 = fmaf(K16[i], u[i],t16);
    }
    vj0 = rcp_f(t0); vj1 = rcp_f(t1); vj2 = rcp_f(t2); vj3 = rcp_f(t3);
    v16 = cmask * 16.0f * rcp_f(t16 + 1e-30f + (1.0f - cmask));  // b_16 = A = 16; NaN-guard off-lane
  }

  float* op = out + e*256 + 4*c;
#pragma unroll
  for (int i=0;i<16;++i){
    float4 w;
    w.x = u[i]*Kx[0][i]*vj0;
    w.y = u[i]*Kx[1][i]*vj1;
    w.z = u[i]*Kx[2][i]*vj2;
    w.w = u[i]*Kx[3][i]*vj3;
    *(float4*)(op + i*16) = w;
  }

  const float* bp = bids + e*256 + 4*c;
  float pay[16];
#pragma unroll
  for (int i=0;i<16;++i){
    float4 bb = *(const float4*)(bp + i*16);
    float s = u[i]*(Kx[0][i]*vj0*bb.x + Kx[1][i]*vj1*bb.y + Kx[2][i]*vj2*bb.z + Kx[3][i]*vj3*bb.w);
    pay[i] = qadd2(s);
  }
  float4 pv;
  if      (c==0) pv = make_float4(pay[0],pay[1],pay[2],pay[3]);
  else if (c==1) pv = make_float4(pay[4],pay[5],pay[6],pay[7]);
  else if (c==2) pv = make_float4(pay[8],pay[9],pay[10],pay[11]);
  else           pv = make_float4(pay[12],pay[13],pay[14],pay[15]);
  const float4 fr = *(const float4*)(fracv + e*16 + 4*c);
  pv.x *= fr.x; pv.y *= fr.y; pv.z *= fr.z; pv.w *= fr.w;
  *(float4*)(out + (size_t)NB*256 + e*16 + 4*c) = pv;
}

// ================= launch =================
extern "C" void kernel_launch(void* const* d_in, const int* in_sizes, int n_in,
                              void* d_out, int out_size, void* d_ws, size_t ws_size,
                              hipStream_t stream)
{
  const float* bids = (const float*)d_in[0];
  const float* aw0 = (const float*)d_in[1];  const float* ab0 = (const float*)d_in[2];
  const float* aw1 = (const float*)d_in[3];  const float* ab1 = (const float*)d_in[4];
  const float* aw2 = (const float*)d_in[5];  const float* ab2 = (const float*)d_in[6];
  const float* aw3 = (const float*)d_in[7];  const float* ab3 = (const float*)d_in[8];
  const float* pw0 = (const float*)d_in[9];  const float* pb0 = (const float*)d_in[10];
  const float* pw1 = (const float*)d_in[11]; const float* pb1 = (const float*)d_in[12];
  const float* pw2 = (const float*)d_in[13]; const float* pb2 = (const float*)d_in[14];
  const float* pw3 = (const float*)d_in[15]; const float* pb3 = (const float*)d_in[16];

  float* aug   = (float*)d_ws;                       // NB*256 f32
  float* fracv = aug + (size_t)NB*256;               // NB*16 f32

  // f16 transposed/split weights live in d_out's payments region (consumed by mlp_mfma
  // before sinkhorn overwrites payments — stream-ordered, graph-capture safe)
  _Float16* WT = (_Float16*)((float*)d_out + (size_t)NB*256);

  PrepJobs js;
  js.j[0] = { aw0, WT+O_AW0H, nullptr,    8, 32768 };
  js.j[1] = { aw1, WT+O_AW1H, WT+O_AW1L,  7, 16384 };
  js.j[2] = { aw2, WT+O_AW2H, WT+O_AW2L,  7, 16384 };
  js.j[3] = { aw3, WT+O_AW3H, WT+O_AW3L,  7, 32768 };
  js.j[4] = { pw0, WT+O_PW0H, nullptr,    8, 32768 };
  js.j[5] = { pw1, WT+O_PW1H, nullptr,    7, 16384 };
  js.j[6] = { pw2, WT+O_PW2H, nullptr,    7, 16384 };
  js.j[7] = { pw3, WT+O_PW3H, nullptr,    7, 2048  };

  prep_kernel<<<dim3(128,8), 256, 0, stream>>>(js);
  mlp_mfma<<<dim3(NB/32), 128, 0, stream>>>(bids, WT, ab0,ab1,ab2,ab3, pb0,pb1,pb2,pb3, aug, fracv);
  sinkhorn_kernel<<<dim3(NB/64), 256, 0, stream>>>(aug, bids, fracv, (float*)d_out);
}

// Round 5
// 249.136 us; speedup vs baseline: 1.3947x; 1.0553x over previous
//
#include <hip/hip_runtime.h>

#define NB 32768

typedef _Float16 half8 __attribute__((ext_vector_type(8)));
typedef float floatx4 __attribute__((ext_vector_type(4)));
typedef unsigned int uint4v __attribute__((ext_vector_type(4)));

#define MFMA16(a,b,c) __builtin_amdgcn_mfma_f32_16x16x32_f16(a,b,c,0,0,0)

// ---------- fast math ----------
__device__ __forceinline__ float rcp_f(float x){ return __builtin_amdgcn_rcpf(x); }
__device__ __forceinline__ float exp2_f(float x){ return __builtin_amdgcn_exp2f(x); }
__device__ __forceinline__ float tanh_f(float x){
  float e = exp2_f(x * 2.8853900817779268f);     // e^(2x)
  return (e - 1.0f) * rcp_f(e + 1.0f);
}
__device__ __forceinline__ float sigmoid_f(float x){
  return rcp_f(1.0f + exp2_f(-1.4426950408889634f * x));
}

// DPP quad butterflies: xor1 = quad_perm[1,0,3,2]=0xB1, xor2 = [2,3,0,1]=0x4E
template<int CTRL>
__device__ __forceinline__ float dpp_qp(float x){
  return __builtin_bit_cast(float, __builtin_amdgcn_update_dpp(0, __builtin_bit_cast(int,x), CTRL, 0xF, 0xF, true));
}
__device__ __forceinline__ float qadd2(float x){
  x += dpp_qp<0xB1>(x);
  x += dpp_qp<0x4E>(x);
  return x;
}
__device__ __forceinline__ float qmax2(float x){
  x = fmaxf(x, dpp_qp<0xB1>(x));
  x = fmaxf(x, dpp_qp<0x4E>(x));
  return x;
}

// ---------- f16 weight region offsets (in _Float16 units), lives in d_ws ----------
constexpr int O_AW0H = 0;        // 256x128
constexpr int O_AW1H = 32768;    // 128x128
constexpr int O_AW2H = 49152;
constexpr int O_AW3H = 65536;    // 128x256
constexpr int O_PW0H = 98304;
constexpr int O_PW1H = 131072;
constexpr int O_PW2H = 147456;
constexpr int O_PW3H = 163840;   // 128x16
constexpr int O_AW1L = 165888;
constexpr int O_AW2L = 182272;
constexpr int O_AW3L = 198656;

// ---------- weight prep: transpose + split f32 -> f16 hi/lo ----------
struct PrepJob { const float* src; _Float16* h; _Float16* l; int kshift; int total; };
struct PrepJobs { PrepJob j[8]; };

__global__ void prep_kernel(PrepJobs js){
  const PrepJob jb = js.j[blockIdx.y];
  const int idx = blockIdx.x*256 + threadIdx.x;
  if (idx >= jb.total) return;
  const int K = 1 << jb.kshift;
  const int n = idx >> jb.kshift;
  const int k = idx & (K-1);
  const int N = jb.total >> jb.kshift;
  float w = jb.src[(long)k*N + n];
  _Float16 h = (_Float16)w;
  jb.h[idx] = h;
  if (jb.l) jb.l[idx] = (_Float16)(w - (float)h);
}

// ---------- LDS activation layout: 16 rows x 128 cols of packed (hi|lo) u32 ----------
// 16B-chunk XOR swizzle by (row&7)
__device__ __forceinline__ int aaddr(int row, int col){
  int cc = (col >> 2) ^ (row & 7);
  return row*128 + (cc<<2) + (col & 3);
}

template<bool NEED_LO>
__device__ __forceinline__ void read_frag(const unsigned int* __restrict__ act,
    int row, int ks, int q, half8& ah, half8& al)
{
  const int s = row & 7;
  const int cc0 = ks*8 + q*2;
  uint4v c0 = *(const uint4v*)(act + row*128 + (((cc0  ) ^ s)<<2));
  uint4v c1 = *(const uint4v*)(act + row*128 + (((cc0+1) ^ s)<<2));
  uint4v h;
  h.x = (c0.x & 0xffffu) | (c0.y << 16);
  h.y = (c0.z & 0xffffu) | (c0.w << 16);
  h.z = (c1.x & 0xffffu) | (c1.y << 16);
  h.w = (c1.z & 0xffffu) | (c1.w << 16);
  ah = __builtin_bit_cast(half8, h);
  if constexpr (NEED_LO){
    uint4v g;
    g.x = (c0.x >> 16) | (c0.y & 0xffff0000u);
    g.y = (c0.z >> 16) | (c0.w & 0xffff0000u);
    g.z = (c1.x >> 16) | (c1.y & 0xffff0000u);
    g.w = (c1.z >> 16) | (c1.w & 0xffff0000u);
    al = __builtin_bit_cast(half8, g);
  }
}

__device__ __forceinline__ unsigned int pack_act(float v){
  _Float16 h = (_Float16)v;
  _Float16 lo = (_Float16)(v - (float)h);
  return (unsigned int)__builtin_bit_cast(unsigned short, h)
       | ((unsigned int)__builtin_bit_cast(unsigned short, lo) << 16);
}

__device__ __forceinline__ half8 load_xfrag(const float* __restrict__ X, long row, int k0){
  float4 a = *(const float4*)(X + row*256 + k0);
  float4 b = *(const float4*)(X + row*256 + k0 + 4);
  half8 h;
  h[0]=(_Float16)a.x; h[1]=(_Float16)a.y; h[2]=(_Float16)a.z; h[3]=(_Float16)a.w;
  h[4]=(_Float16)b.x; h[5]=(_Float16)b.y; h[6]=(_Float16)b.z; h[7]=(_Float16)b.w;
  return h;
}

// ---------- MFMA inner block: 1 m-tile x NT n-tiles, K = KS*32 ----------
template<int KS, int PASSES, int NT>
__device__ __forceinline__ void mfma_block(
    const half8* Ah, const half8* Al,
    const _Float16* __restrict__ Wh, const _Float16* __restrict__ Wl,
    int K, int l15, int q, floatx4* acc)
{
#pragma unroll
  for (int nt=0; nt<NT; ++nt){
    const _Float16* bp = Wh + (nt*16 + l15)*K + q*8;
#pragma unroll
    for (int ks=0; ks<KS; ++ks){
      half8 bh = *(const half8*)(bp + ks*32);
      acc[nt] = MFMA16(Ah[ks], bh, acc[nt]);
      if constexpr (PASSES == 3){
        const _Float16* blp = Wl + (nt*16 + l15)*K + q*8;
        half8 bl = *(const half8*)(blp + ks*32);
        acc[nt] = MFMA16(Al[ks], bh, acc[nt]);
        acc[nt] = MFMA16(Ah[ks], bl, acc[nt]);
      }
    }
  }
}

// epilogue: bias+tanh+pack to LDS; rows q*4 + r
__device__ __forceinline__ void epi_tanh(floatx4* acc, const float* __restrict__ bias,
    unsigned int* __restrict__ act, int q, int l15)
{
#pragma unroll
  for (int nt=0; nt<8; ++nt){
    float bb = bias[nt*16 + l15];
#pragma unroll
    for (int r=0; r<4; ++r){
      float t = tanh_f(acc[nt][r] + bb);
      act[aaddr(q*4 + r, nt*16 + l15)] = pack_act(t);
    }
  }
}

template<int PASSES>
__device__ __forceinline__ void hidden128(unsigned int* __restrict__ act,
    const _Float16* __restrict__ Wh, const _Float16* __restrict__ Wl,
    const float* __restrict__ bias, int q, int l15)
{
  half8 Ah[4], Al[4];
#pragma unroll
  for (int ks=0; ks<4; ++ks)
    read_frag<PASSES==3>(act, l15, ks, q, Ah[ks], Al[ks]);
  floatx4 acc[8];
#pragma unroll
  for (int nt=0; nt<8; ++nt) acc[nt] = (floatx4)0.0f;
  mfma_block<4,PASSES,8>(Ah, Al, Wh, Wl, 128, l15, q, acc);
  epi_tanh(acc, bias, act, q, l15);
}

// ================= Fused kernel: MLPs + Sinkhorn + payments =================
// 64 threads = 1 wave per block, 16 rows/block. Zero barriers (all LDS traffic is
// wave-local; LDS ops execute in issue order within a wave).
// LDS map: S[0..2048) = act_a (u32 hi|lo), S[2048..4096) = act_p,
//          S[0..4096) REUSED as aug f32 (16 rows x 256) after pL4 (act_p dead) and
//          after aL4 pre-loads act_a into registers. S[4096..4352) = frac f32.
__global__ __launch_bounds__(64, 2) void fused_kernel(
  const float* __restrict__ X, const _Float16* __restrict__ WT,
  const float* __restrict__ ab0, const float* __restrict__ ab1,
  const float* __restrict__ ab2, const float* __restrict__ ab3,
  const float* __restrict__ pb0, const float* __restrict__ pb1,
  const float* __restrict__ pb2, const float* __restrict__ pb3,
  float* __restrict__ out)
{
  __shared__ unsigned int S[16*256 + 256];   // 17408 B
  unsigned int* act_a = S;
  unsigned int* act_p = S + 2048;
  float* frac_l = (float*)(S + 4096);
  const int l = threadIdx.x, q = l>>4, l15 = l&15;
  const long rb = (long)blockIdx.x * 16;

  // ---- L1 of both nets from one X fragment set (K=256) ----
  {
    half8 Xf[8];
#pragma unroll
    for (int ks=0; ks<8; ++ks)
      Xf[ks] = load_xfrag(X, rb + l15, ks*32 + q*8);
    floatx4 acca[8], accp[8];
#pragma unroll
    for (int nt=0; nt<8; ++nt){ acca[nt] = (floatx4)0.0f; accp[nt] = (floatx4)0.0f; }
    mfma_block<8,1,8>(Xf, Xf, WT+O_AW0H, WT+O_AW0H, 256, l15, q, acca);
    mfma_block<8,1,8>(Xf, Xf, WT+O_PW0H, WT+O_PW0H, 256, l15, q, accp);
    epi_tanh(acca, ab0, act_a, q, l15);
    epi_tanh(accp, pb0, act_p, q, l15);
  }
  // ---- hidden layers interleaved: a (3-pass split-corrected), p (1-pass) ----
  hidden128<3>(act_a, WT+O_AW1H, WT+O_AW1L, ab1, q, l15);
  hidden128<1>(act_p, WT+O_PW1H, WT+O_PW1H, pb1, q, l15);
  hidden128<3>(act_a, WT+O_AW2H, WT+O_AW2L, ab2, q, l15);
  hidden128<1>(act_p, WT+O_PW2H, WT+O_PW2H, pb2, q, l15);

  // ---- p-net L4 -> frac (sigmoid) to LDS — MUST precede aL4's aug overlay ----
  {
    half8 Ah[4], Al[4];
#pragma unroll
    for (int ks=0; ks<4; ++ks)
      read_frag<false>(act_p, l15, ks, q, Ah[ks], Al[ks]);
    floatx4 acc1 = (floatx4)0.0f;
    mfma_block<4,1,1>(Ah, Ah, WT+O_PW3H, WT+O_PW3H, 128, l15, q, &acc1);
    float bb = pb3[l15];
#pragma unroll
    for (int r=0; r<4; ++r)
      frac_l[(q*4+r)*16 + l15] = sigmoid_f(acc1[r] + bb);
  }
  // ---- a-net L4 -> aug (f32) into LDS overlay; act_a fully pre-read to regs ----
  {
    half8 Ah[4], Al[4];
#pragma unroll
    for (int ks=0; ks<4; ++ks)
      read_frag<true>(act_a, l15, ks, q, Ah[ks], Al[ks]);
    float* augl = (float*)S;
#pragma unroll
    for (int hf=0; hf<2; ++hf){
      floatx4 acc[8];
#pragma unroll
      for (int nt=0; nt<8; ++nt) acc[nt] = (floatx4)0.0f;
      mfma_block<4,3,8>(Ah, Al, WT+O_AW3H + hf*128*128, WT+O_AW3L + hf*128*128, 128, l15, q, acc);
      const int ncol0 = hf*128;
#pragma unroll
      for (int nt=0; nt<8; ++nt){
        float bb = ab3[ncol0 + nt*16 + l15];
#pragma unroll
        for (int r=0; r<4; ++r)
          augl[(q*4+r)*256 + ncol0 + nt*16 + l15] = acc[nt][r] + bb;
      }
    }
  }

  // ================= Sinkhorn + payments (wave-local) =================
  const int c = l & 3;
  const int eL = l >> 2;                 // local element 0..15
  const long e = rb + eL;                // global element
  const float Ssc = 14.426950408889634f; // (1/EPS)/ln2 : logits in exp2 units
  const float cmask = (c == 3) ? 1.0f : 0.0f;

  float Kx[4][17];   // owned columns (4c+cc), rows 0..16 (row 16 = pad row, logit 0)
  float K16[17];     // pad column 16 (lane 3 only; zeroed elsewhere)

  const float* ap = (const float*)S + eL*256 + 4*c;
#pragma unroll
  for (int i=0;i<16;++i){
    float4 v = *(const float4*)(ap + i*16);
    Kx[0][i]=v.x*Ssc; Kx[1][i]=v.y*Ssc; Kx[2][i]=v.z*Ssc; Kx[3][i]=v.w*Ssc;
  }
  Kx[0][16]=0.f; Kx[1][16]=0.f; Kx[2][16]=0.f; Kx[3][16]=0.f;

  float u[17];
#pragma unroll
  for (int i=0;i<17;++i){
    float mm = fmaxf(fmaxf(Kx[0][i],Kx[1][i]), fmaxf(Kx[2][i],Kx[3][i]));
    mm = fmaxf(mm, 0.0f);
    mm = qmax2(mm);
    Kx[0][i] = exp2_f(Kx[0][i]-mm);
    Kx[1][i] = exp2_f(Kx[1][i]-mm);
    Kx[2][i] = exp2_f(Kx[2][i]-mm);
    Kx[3][i] = exp2_f(Kx[3][i]-mm);
    K16[i]   = cmask * exp2_f(-mm);
  }

  float vj0=1.f, vj1=1.f, vj2=1.f, vj3=1.f;
  float v16 = cmask;

  for (int r=0;r<40;++r){
#pragma unroll
    for (int i=0;i<17;++i){
      float p = Kx[0][i]*vj0 + Kx[1][i]*vj1 + Kx[2][i]*vj2 + Kx[3][i]*vj3 + K16[i]*v16;
      p = qadd2(p);
      u[i] = rcp_f(p);
    }
    u[16] *= 16.0f;   // a_16 = I = 16
    float t0=0.f,t1=0.f,t2=0.f,t3=0.f,t16=0.f;
#pragma unroll
    for (int i=0;i<17;++i){
      t0  = fmaf(Kx[0][i],u[i],t0);
      t1  = fmaf(Kx[1][i],u[i],t1);
      t2  = fmaf(Kx[2][i],u[i],t2);
      t3  = fmaf(Kx[3][i],u[i],t3);
      t16 = fmaf(K16[i], u[i],t16);
    }
    vj0 = rcp_f(t0); vj1 = rcp_f(t1); vj2 = rcp_f(t2); vj3 = rcp_f(t3);
    v16 = cmask * 16.0f * rcp_f(t16 + 1e-30f + (1.0f - cmask));  // b_16 = A = 16; NaN-guard off-lane
  }

  // allocs = u_i * K_ij * v_j  (real 16x16 block)
  float* op = out + e*256 + 4*c;
#pragma unroll
  for (int i=0;i<16;++i){
    float4 w;
    w.x = u[i]*Kx[0][i]*vj0;
    w.y = u[i]*Kx[1][i]*vj1;
    w.z = u[i]*Kx[2][i]*vj2;
    w.w = u[i]*Kx[3][i]*vj3;
    *(float4*)(op + i*16) = w;
  }

  // payments_i = frac_i * sum_j allocs_ij * bids_ij   (bids re-read from global, L1/L3-hot)
  const float* bp = X + e*256 + 4*c;
  float pay[16];
#pragma unroll
  for (int i=0;i<16;++i){
    float4 bb = *(const float4*)(bp + i*16);
    float s = u[i]*(Kx[0][i]*vj0*bb.x + Kx[1][i]*vj1*bb.y + Kx[2][i]*vj2*bb.z + Kx[3][i]*vj3*bb.w);
    pay[i] = qadd2(s);
  }
  float4 pv;
  if      (c==0) pv = make_float4(pay[0],pay[1],pay[2],pay[3]);
  else if (c==1) pv = make_float4(pay[4],pay[5],pay[6],pay[7]);
  else if (c==2) pv = make_float4(pay[8],pay[9],pay[10],pay[11]);
  else           pv = make_float4(pay[12],pay[13],pay[14],pay[15]);
  const float4 fr = *(const float4*)(frac_l + eL*16 + 4*c);
  pv.x *= fr.x; pv.y *= fr.y; pv.z *= fr.z; pv.w *= fr.w;
  *(float4*)(out + (size_t)NB*256 + e*16 + 4*c) = pv;
}

// ================= launch =================
extern "C" void kernel_launch(void* const* d_in, const int* in_sizes, int n_in,
                              void* d_out, int out_size, void* d_ws, size_t ws_size,
                              hipStream_t stream)
{
  const float* bids = (const float*)d_in[0];
  const float* aw0 = (const float*)d_in[1];  const float* ab0 = (const float*)d_in[2];
  const float* aw1 = (const float*)d_in[3];  const float* ab1 = (const float*)d_in[4];
  const float* aw2 = (const float*)d_in[5];  const float* ab2 = (const float*)d_in[6];
  const float* aw3 = (const float*)d_in[7];  const float* ab3 = (const float*)d_in[8];
  const float* pw0 = (const float*)d_in[9];  const float* pb0 = (const float*)d_in[10];
  const float* pw1 = (const float*)d_in[11]; const float* pb1 = (const float*)d_in[12];
  const float* pw2 = (const float*)d_in[13]; const float* pb2 = (const float*)d_in[14];
  const float* pw3 = (const float*)d_in[15]; const float* pb3 = (const float*)d_in[16];

  // f16 transposed/split weights in workspace (no d_out aliasing — fused kernel
  // writes payments while other blocks still read WT)
  _Float16* WT = (_Float16*)d_ws;

  PrepJobs js;
  js.j[0] = { aw0, WT+O_AW0H, nullptr,    8, 32768 };
  js.j[1] = { aw1, WT+O_AW1H, WT+O_AW1L,  7, 16384 };
  js.j[2] = { aw2, WT+O_AW2H, WT+O_AW2L,  7, 16384 };
  js.j[3] = { aw3, WT+O_AW3H, WT+O_AW3L,  7, 32768 };
  js.j[4] = { pw0, WT+O_PW0H, nullptr,    8, 32768 };
  js.j[5] = { pw1, WT+O_PW1H, nullptr,    7, 16384 };
  js.j[6] = { pw2, WT+O_PW2H, nullptr,    7, 16384 };
  js.j[7] = { pw3, WT+O_PW3H, nullptr,    7, 2048  };

  prep_kernel<<<dim3(128,8), 256, 0, stream>>>(js);
  fused_kernel<<<dim3(NB/16), 64, 0, stream>>>(bids, WT, ab0,ab1,ab2,ab3,
                                               pb0,pb1,pb2,pb3, (float*)d_out);
}